// Round 1
// baseline (1183.287 us; speedup 1.0000x reference)
//
#include <hip/hip_runtime.h>

typedef __bf16 bf16_t;
typedef bf16_t bf16x8 __attribute__((ext_vector_type(8)));
typedef float  f32x4  __attribute__((ext_vector_type(4)));

constexpr int Bb  = 4;
constexpr int Din = 256;
constexpr int Ss  = 2048;
constexpr int Dm  = 512;
constexpr int Hh  = 8;
constexpr int Dk  = 64;
constexpr int NHd = 32;     // B*H
constexpr float LOG2E = 1.44269504088896340736f;

#define MFMA16(a, b, c) __builtin_amdgcn_mfma_f32_16x16x32_bf16((a), (b), (c), 0, 0, 0)

__device__ __forceinline__ void fsplit(float x, bf16_t& h, bf16_t& l) {
    bf16_t hh = (bf16_t)x;
    h = hh;
    l = (bf16_t)(x - (float)hh);
}
__device__ __forceinline__ bf16x8 ldfrag(const bf16_t* p) {
    return *reinterpret_cast<const bf16x8*>(p);
}

// ---------------------------------------------------------------------------
// prep_x: x [B][DIN][S] fp32 -> xt hi/lo [B][S][DIN] bf16 (transpose + split)
// ---------------------------------------------------------------------------
__global__ void prep_x(const float* __restrict__ x, bf16_t* __restrict__ xh,
                       bf16_t* __restrict__ xl) {
    __shared__ float t[32][33];
    int b = blockIdx.z, i0 = blockIdx.y * 32, s0 = blockIdx.x * 32;
    int tx = threadIdx.x, ty = threadIdx.y;  // 32 x 8
    const float* xb = x + ((size_t)b * Din + i0) * Ss + s0;
#pragma unroll
    for (int r = 0; r < 4; ++r) t[ty + r * 8][tx] = xb[(size_t)(ty + r * 8) * Ss + tx];
    __syncthreads();
#pragma unroll
    for (int r = 0; r < 4; ++r) {
        int srow = ty + r * 8;
        float v = t[tx][srow];
        size_t o = ((size_t)b * Ss + s0 + srow) * Din + i0 + tx;
        bf16_t h, l;
        fsplit(v, h, l);
        xh[o] = h;
        xl[o] = l;
    }
}

// ---------------------------------------------------------------------------
// prep_w: split Wq/Wk into bf16 hi/lo, cast Wv/Wo to bf16 hi. All are 512*256.
// ---------------------------------------------------------------------------
__global__ void prep_w(const float* __restrict__ Wq, const float* __restrict__ Wk,
                       const float* __restrict__ Wv, const float* __restrict__ Wo,
                       bf16_t* wqh, bf16_t* wql, bf16_t* wkh, bf16_t* wkl,
                       bf16_t* wvh, bf16_t* woh) {
    int e = blockIdx.x * 256 + threadIdx.x;  // grid covers exactly 512*256
    bf16_t h, l;
    fsplit(Wq[e], h, l); wqh[e] = h; wql[e] = l;
    fsplit(Wk[e], h, l); wkh[e] = h; wkl[e] = l;
    wvh[e] = (bf16_t)Wv[e];
    woh[e] = (bf16_t)Wo[e];
}

// ---------------------------------------------------------------------------
// proj_qk: C[s][m] = xt_b @ W^T + bias, split-bf16 (3-MFMA) fp32-accurate.
// Stores head-layout [n=b*8+h][s][d] hi/lo bf16. Wave = 64s x 64m tile.
// ---------------------------------------------------------------------------
__global__ void proj_qk(const bf16_t* __restrict__ xh, const bf16_t* __restrict__ xl,
                        const bf16_t* __restrict__ wh, const bf16_t* __restrict__ wl,
                        const float* __restrict__ bias,
                        bf16_t* __restrict__ outh, bf16_t* __restrict__ outl) {
    int b = blockIdx.y;
    int mt = blockIdx.x & 7, sb = blockIdx.x >> 3;
    int wave = threadIdx.x >> 6, lane = threadIdx.x & 63;
    int l15 = lane & 15, quad = lane >> 4;
    int s0 = sb * 256 + wave * 64, m0 = mt * 64;
    const bf16_t* xhb = xh + ((size_t)b * Ss + s0 + l15) * Din + quad * 8;
    const bf16_t* xlb = xl + ((size_t)b * Ss + s0 + l15) * Din + quad * 8;
    const bf16_t* whb = wh + (size_t)(m0 + l15) * Din + quad * 8;
    const bf16_t* wlb = wl + (size_t)(m0 + l15) * Din + quad * 8;
    f32x4 acc[4][4] = {};  // [s-tile][m-tile]
    for (int ks = 0; ks < 8; ++ks) {
        bf16x8 ah[4], al[4], bh[4], bl[4];
#pragma unroll
        for (int st = 0; st < 4; ++st) {
            ah[st] = ldfrag(xhb + (size_t)st * 16 * Din + ks * 32);
            al[st] = ldfrag(xlb + (size_t)st * 16 * Din + ks * 32);
        }
#pragma unroll
        for (int nt = 0; nt < 4; ++nt) {
            bh[nt] = ldfrag(whb + (size_t)nt * 16 * Din + ks * 32);
            bl[nt] = ldfrag(wlb + (size_t)nt * 16 * Din + ks * 32);
        }
#pragma unroll
        for (int st = 0; st < 4; ++st)
#pragma unroll
            for (int nt = 0; nt < 4; ++nt) {
                acc[st][nt] = MFMA16(ah[st], bh[nt], acc[st][nt]);
                acc[st][nt] = MFMA16(ah[st], bl[nt], acc[st][nt]);
                acc[st][nt] = MFMA16(al[st], bh[nt], acc[st][nt]);
            }
    }
    int h = m0 >> 6;  // head within this b (m-range is 64-aligned)
#pragma unroll
    for (int nt = 0; nt < 4; ++nt) {
        int m = m0 + nt * 16 + l15;
        float bb = bias[m];
        int d = m & 63;
#pragma unroll
        for (int st = 0; st < 4; ++st)
#pragma unroll
            for (int r = 0; r < 4; ++r) {
                int s = s0 + st * 16 + quad * 4 + r;
                float v = acc[st][nt][r] + bb;
                bf16_t hh, ll;
                fsplit(v, hh, ll);
                size_t o = ((size_t)(b * Hh + h) * Ss + s) * Dk + d;
                outh[o] = hh;
                outl[o] = ll;
            }
    }
}

// ---------------------------------------------------------------------------
// proj_v: C[m][s] = Wv @ xt_b^T + bias, plain bf16. Stores Vt [n][d][s] bf16.
// ---------------------------------------------------------------------------
__global__ void proj_v(const bf16_t* __restrict__ xh, const bf16_t* __restrict__ wvh,
                       const float* __restrict__ bias, bf16_t* __restrict__ vt) {
    int b = blockIdx.y;
    int mt = blockIdx.x & 7, sb = blockIdx.x >> 3;
    int wave = threadIdx.x >> 6, lane = threadIdx.x & 63;
    int l15 = lane & 15, quad = lane >> 4;
    int m0 = mt * 64, s0 = sb * 256 + wave * 64;
    const bf16_t* ab = wvh + (size_t)(m0 + l15) * Din + quad * 8;
    const bf16_t* bb = xh + ((size_t)b * Ss + s0 + l15) * Din + quad * 8;
    f32x4 acc[4][4] = {};  // [m-tile][s-tile]
    for (int ks = 0; ks < 8; ++ks) {
        bf16x8 af[4], bf_[4];
#pragma unroll
        for (int i = 0; i < 4; ++i) {
            af[i] = ldfrag(ab + (size_t)i * 16 * Din + ks * 32);
            bf_[i] = ldfrag(bb + (size_t)i * 16 * Din + ks * 32);
        }
#pragma unroll
        for (int i = 0; i < 4; ++i)
#pragma unroll
            for (int j = 0; j < 4; ++j) acc[i][j] = MFMA16(af[i], bf_[j], acc[i][j]);
    }
#pragma unroll
    for (int i = 0; i < 4; ++i)
#pragma unroll
        for (int r = 0; r < 4; ++r) {
            int m = m0 + i * 16 + quad * 4 + r;
            float bv = bias[m];
#pragma unroll
            for (int j = 0; j < 4; ++j) {
                int s = s0 + j * 16 + l15;
                vt[((size_t)b * Dm + m) * Ss + s] = (bf16_t)(acc[i][j][r] + bv);
            }
        }
}

// ---------------------------------------------------------------------------
// attn_kernel: per (head, 64-q tile). Wave owns 16 q-rows, sweeps all 2048 keys.
// Pass 1: l = sum exp(s) (split-bf16 scores). Pass 2: recompute scores, write
// normalized w to d_out (fp32, NON-TEMPORAL: never re-read, keep K/V in L2),
// P through LDS, accumulate P@V, store AO bf16.
// ---------------------------------------------------------------------------
__global__ void attn_kernel(const bf16_t* __restrict__ Qhi, const bf16_t* __restrict__ Qlo,
                            const bf16_t* __restrict__ Khi, const bf16_t* __restrict__ Klo,
                            const bf16_t* __restrict__ Vt, bf16_t* __restrict__ AO,
                            float* __restrict__ attw) {
    __shared__ __align__(16) bf16_t pbuf[4][16][72];
    int head = blockIdx.y, qt = blockIdx.x;
    int wave = threadIdx.x >> 6, lane = threadIdx.x & 63;
    int l15 = lane & 15, quad = lane >> 4;
    int q0 = qt * 64 + wave * 16;

    const bf16_t* qh_p = Qhi + ((size_t)head * Ss + q0 + l15) * Dk + quad * 8;
    const bf16_t* ql_p = Qlo + ((size_t)head * Ss + q0 + l15) * Dk + quad * 8;
    bf16x8 qah[2], qal[2];
#pragma unroll
    for (int ks = 0; ks < 2; ++ks) {
        qah[ks] = ldfrag(qh_p + ks * 32);
        qal[ks] = ldfrag(ql_p + ks * 32);
    }
    const bf16_t* kh_b = Khi + (size_t)head * Ss * Dk;
    const bf16_t* kl_b = Klo + (size_t)head * Ss * Dk;
    const bf16_t* v_b  = Vt + (size_t)head * Dk * Ss;

    // ---- pass 1: row sums of exp(s) (no max trick: |s| <~ 16, fp32-safe) ----
    float lsum[4] = {0.f, 0.f, 0.f, 0.f};
    for (int kc = 0; kc < Ss; kc += 64) {
        __syncthreads();  // keep 4 waves in lockstep for L1 reuse of K chunk
#pragma unroll
        for (int nt = 0; nt < 4; ++nt) {
            int k0 = kc + nt * 16;
            const bf16_t* kh_p = kh_b + (size_t)(k0 + l15) * Dk + quad * 8;
            const bf16_t* kl_p = kl_b + (size_t)(k0 + l15) * Dk + quad * 8;
            f32x4 sc = {0.f, 0.f, 0.f, 0.f};
#pragma unroll
            for (int ks = 0; ks < 2; ++ks) {
                bf16x8 kbh = ldfrag(kh_p + ks * 32);
                bf16x8 kbl = ldfrag(kl_p + ks * 32);
                sc = MFMA16(qah[ks], kbh, sc);
                sc = MFMA16(qah[ks], kbl, sc);
                sc = MFMA16(qal[ks], kbh, sc);
            }
#pragma unroll
            for (int r = 0; r < 4; ++r) lsum[r] += __builtin_amdgcn_exp2f(sc[r] * LOG2E);
        }
    }
#pragma unroll
    for (int r = 0; r < 4; ++r) {  // merge across the 16 column-lanes
        float v = lsum[r];
        v += __shfl_xor(v, 1);
        v += __shfl_xor(v, 2);
        v += __shfl_xor(v, 4);
        v += __shfl_xor(v, 8);
        lsum[r] = v;
    }
    float linv[4];
#pragma unroll
    for (int r = 0; r < 4; ++r) linv[r] = 1.0f / lsum[r];

    // ---- pass 2 ----
    f32x4 oacc[4] = {};  // [d-tile] C[16q][16d]
    float* aw_base = attw + ((size_t)head * Ss + q0) * Ss;
    for (int kc = 0; kc < Ss; kc += 64) {
        __syncthreads();
#pragma unroll
        for (int nt = 0; nt < 4; ++nt) {
            int k0 = kc + nt * 16;
            const bf16_t* kh_p = kh_b + (size_t)(k0 + l15) * Dk + quad * 8;
            const bf16_t* kl_p = kl_b + (size_t)(k0 + l15) * Dk + quad * 8;
            f32x4 sc = {0.f, 0.f, 0.f, 0.f};
#pragma unroll
            for (int ks = 0; ks < 2; ++ks) {
                bf16x8 kbh = ldfrag(kh_p + ks * 32);
                bf16x8 kbl = ldfrag(kl_p + ks * 32);
                sc = MFMA16(qah[ks], kbh, sc);
                sc = MFMA16(qah[ks], kbl, sc);
                sc = MFMA16(qal[ks], kbh, sc);
            }
#pragma unroll
            for (int r = 0; r < 4; ++r) {
                float w = __builtin_amdgcn_exp2f(sc[r] * LOG2E) * linv[r];
                int q = quad * 4 + r;
                __builtin_nontemporal_store(w, &aw_base[(size_t)q * Ss + k0 + l15]);
                pbuf[wave][q][nt * 16 + l15] = (bf16_t)w;
            }
        }
        // P @ V over this 64-key chunk
#pragma unroll
        for (int ks = 0; ks < 2; ++ks) {
            bf16x8 pa = *reinterpret_cast<const bf16x8*>(&pbuf[wave][l15][ks * 32 + quad * 8]);
#pragma unroll
            for (int dt = 0; dt < 4; ++dt) {
                bf16x8 vb = ldfrag(v_b + (size_t)(dt * 16 + l15) * Ss + kc + ks * 32 + quad * 8);
                oacc[dt] = MFMA16(pa, vb, oacc[dt]);
            }
        }
    }
    // store AO: flat [s'][n][d] bf16 (torch-faithful flat layout)
#pragma unroll
    for (int dt = 0; dt < 4; ++dt)
#pragma unroll
        for (int r = 0; r < 4; ++r) {
            int q = q0 + quad * 4 + r;
            int col = head * Dk + dt * 16 + l15;
            AO[(size_t)q * (NHd * Dk) + col] = (bf16_t)oacc[dt][r];
        }
}

// ---------------------------------------------------------------------------
// out_kernel: Z[b][i][s] = sum_e Wo[i][e] * AO_scrambled[b][s][e] + bo[i]
// AO row base for (b,s): (b*512 + s/4)*2048 + (s%4)*512  (contiguous in e!)
// ---------------------------------------------------------------------------
__global__ void out_kernel(const bf16_t* __restrict__ AO, const bf16_t* __restrict__ woh,
                           const float* __restrict__ bo, float* __restrict__ Z) {
    int b = blockIdx.z, it = blockIdx.y, sb = blockIdx.x;
    int wave = threadIdx.x >> 6, lane = threadIdx.x & 63;
    int l15 = lane & 15, quad = lane >> 4;
    int i0 = it * 64, s0 = sb * 256 + wave * 64;
    const bf16_t* wop = woh + (size_t)(i0 + l15) * Dm + quad * 8;
    size_t bbase[4];
#pragma unroll
    for (int nt = 0; nt < 4; ++nt) {
        int s = s0 + nt * 16 + l15;
        bbase[nt] = ((size_t)(b * 512 + (s >> 2)) * 2048) + (size_t)(s & 3) * 512 + quad * 8;
    }
    f32x4 acc[4][4] = {};  // [i-tile][s-tile]
    for (int ks = 0; ks < 16; ++ks) {
        bf16x8 af[4], bf_[4];
#pragma unroll
        for (int mt = 0; mt < 4; ++mt) af[mt] = ldfrag(wop + (size_t)mt * 16 * Dm + ks * 32);
#pragma unroll
        for (int nt = 0; nt < 4; ++nt) bf_[nt] = ldfrag(AO + bbase[nt] + ks * 32);
#pragma unroll
        for (int mt = 0; mt < 4; ++mt)
#pragma unroll
            for (int nt = 0; nt < 4; ++nt) acc[mt][nt] = MFMA16(af[mt], bf_[nt], acc[mt][nt]);
    }
#pragma unroll
    for (int mt = 0; mt < 4; ++mt)
#pragma unroll
        for (int r = 0; r < 4; ++r) {
            int i = i0 + mt * 16 + quad * 4 + r;
            float bias = bo[i];
#pragma unroll
            for (int nt = 0; nt < 4; ++nt) {
                int s = s0 + nt * 16 + l15;
                __builtin_nontemporal_store(acc[mt][nt][r] + bias,
                                            &Z[((size_t)b * Din + i) * Ss + s]);
            }
        }
}

// ---------------------------------------------------------------------------
extern "C" void kernel_launch(void* const* d_in, const int* in_sizes, int n_in,
                              void* d_out, int out_size, void* d_ws, size_t ws_size,
                              hipStream_t stream) {
    const float* x  = (const float*)d_in[0];
    const float* Wq = (const float*)d_in[1];
    const float* bq = (const float*)d_in[2];
    const float* Wk = (const float*)d_in[3];
    const float* bk = (const float*)d_in[4];
    const float* Wv = (const float*)d_in[5];
    const float* bv = (const float*)d_in[6];
    const float* Wo = (const float*)d_in[7];
    const float* bo = (const float*)d_in[8];

    float* Z    = (float*)d_out;
    float* attw = Z + (size_t)Bb * Din * Ss;  // 2,097,152 floats in

    char* ws = (char*)d_ws;
    constexpr size_t SZ_XT = (size_t)Bb * Ss * Din * 2;   // 4 MB
    constexpr size_t SZ_W  = (size_t)Dm * Din * 2;        // 256 KB
    constexpr size_t SZ_Q  = (size_t)NHd * Ss * Dk * 2;   // 8 MB
    bf16_t* xh  = (bf16_t*)(ws);
    bf16_t* xl  = (bf16_t*)(ws + SZ_XT);
    bf16_t* wqh = (bf16_t*)(ws + 2 * SZ_XT);
    bf16_t* wql = (bf16_t*)(ws + 2 * SZ_XT + SZ_W);
    bf16_t* wkh = (bf16_t*)(ws + 2 * SZ_XT + 2 * SZ_W);
    bf16_t* wkl = (bf16_t*)(ws + 2 * SZ_XT + 3 * SZ_W);
    bf16_t* wvh = (bf16_t*)(ws + 2 * SZ_XT + 4 * SZ_W);
    bf16_t* woh = (bf16_t*)(ws + 2 * SZ_XT + 5 * SZ_W);
    char* p2 = ws + 2 * SZ_XT + 6 * SZ_W;
    bf16_t* Qhi = (bf16_t*)(p2);
    bf16_t* Qlo = (bf16_t*)(p2 + SZ_Q);
    bf16_t* Khi = (bf16_t*)(p2 + 2 * SZ_Q);
    bf16_t* Klo = (bf16_t*)(p2 + 3 * SZ_Q);
    bf16_t* Vt  = (bf16_t*)(p2 + 4 * SZ_Q);
    bf16_t* AO  = (bf16_t*)(p2 + 5 * SZ_Q);

    prep_x<<<dim3(Ss / 32, Din / 32, Bb), dim3(32, 8), 0, stream>>>(x, xh, xl);
    prep_w<<<dim3((Dm * Din) / 256), dim3(256), 0, stream>>>(Wq, Wk, Wv, Wo, wqh, wql, wkh,
                                                             wkl, wvh, woh);
    proj_qk<<<dim3(64, Bb), dim3(256), 0, stream>>>(xh, xl, wqh, wql, bq, Qhi, Qlo);
    proj_qk<<<dim3(64, Bb), dim3(256), 0, stream>>>(xh, xl, wkh, wkl, bk, Khi, Klo);
    proj_v<<<dim3(64, Bb), dim3(256), 0, stream>>>(xh, wvh, bv, Vt);
    attn_kernel<<<dim3(Ss / 64, NHd), dim3(256), 0, stream>>>(Qhi, Qlo, Khi, Klo, Vt, AO, attw);
    out_kernel<<<dim3(8, 4, Bb), dim3(256), 0, stream>>>(AO, woh, bo, Z);
}

// Round 2
// 1134.374 us; speedup vs baseline: 1.0431x; 1.0431x over previous
//
#include <hip/hip_runtime.h>

typedef __bf16 bf16_t;
typedef bf16_t bf16x8 __attribute__((ext_vector_type(8)));
typedef float  f32x4  __attribute__((ext_vector_type(4)));

constexpr int Bb  = 4;
constexpr int Din = 256;
constexpr int Ss  = 2048;
constexpr int Dm  = 512;
constexpr int Hh  = 8;
constexpr int Dk  = 64;
constexpr int NHd = 32;     // B*H
constexpr float LOG2E = 1.44269504088896340736f;

#define MFMA16(a, b, c) __builtin_amdgcn_mfma_f32_16x16x32_bf16((a), (b), (c), 0, 0, 0)

__device__ __forceinline__ void fsplit(float x, bf16_t& h, bf16_t& l) {
    bf16_t hh = (bf16_t)x;
    h = hh;
    l = (bf16_t)(x - (float)hh);
}
__device__ __forceinline__ bf16x8 ldfrag(const bf16_t* p) {
    return *reinterpret_cast<const bf16x8*>(p);
}

// ---------------------------------------------------------------------------
// prep_x: x [B][DIN][S] fp32 -> xt hi/lo [B][S][DIN] bf16 (transpose + split)
// ---------------------------------------------------------------------------
__global__ void prep_x(const float* __restrict__ x, bf16_t* __restrict__ xh,
                       bf16_t* __restrict__ xl) {
    __shared__ float t[32][33];
    int b = blockIdx.z, i0 = blockIdx.y * 32, s0 = blockIdx.x * 32;
    int tx = threadIdx.x, ty = threadIdx.y;  // 32 x 8
    const float* xb = x + ((size_t)b * Din + i0) * Ss + s0;
#pragma unroll
    for (int r = 0; r < 4; ++r) t[ty + r * 8][tx] = xb[(size_t)(ty + r * 8) * Ss + tx];
    __syncthreads();
#pragma unroll
    for (int r = 0; r < 4; ++r) {
        int srow = ty + r * 8;
        float v = t[tx][srow];
        size_t o = ((size_t)b * Ss + s0 + srow) * Din + i0 + tx;
        bf16_t h, l;
        fsplit(v, h, l);
        xh[o] = h;
        xl[o] = l;
    }
}

// ---------------------------------------------------------------------------
// prep_w: split Wq/Wk into bf16 hi/lo, cast Wv/Wo to bf16 hi. All are 512*256.
// ---------------------------------------------------------------------------
__global__ void prep_w(const float* __restrict__ Wq, const float* __restrict__ Wk,
                       const float* __restrict__ Wv, const float* __restrict__ Wo,
                       bf16_t* wqh, bf16_t* wql, bf16_t* wkh, bf16_t* wkl,
                       bf16_t* wvh, bf16_t* woh) {
    int e = blockIdx.x * 256 + threadIdx.x;  // grid covers exactly 512*256
    bf16_t h, l;
    fsplit(Wq[e], h, l); wqh[e] = h; wql[e] = l;
    fsplit(Wk[e], h, l); wkh[e] = h; wkl[e] = l;
    wvh[e] = (bf16_t)Wv[e];
    woh[e] = (bf16_t)Wo[e];
}

// ---------------------------------------------------------------------------
// proj_qkv: fused Q/K/V projection. blockIdx.y encodes (which, b):
//   which 0: Q = xt @ Wq^T + bq  (split-bf16, hi/lo out, head layout)
//   which 1: K = xt @ Wk^T + bk  (split-bf16, hi/lo out, head layout)
//   which 2: Vt = Wv @ xt^T + bv (plain bf16, [n][d][s] layout)
// One launch -> 768 blocks (3 blocks/CU, 12 waves/CU) instead of 3 serialized
// 256-block launches at 1 block/CU.
// ---------------------------------------------------------------------------
__global__ void proj_qkv(const bf16_t* __restrict__ xh, const bf16_t* __restrict__ xl,
                         const bf16_t* __restrict__ wqh, const bf16_t* __restrict__ wql,
                         const bf16_t* __restrict__ wkh, const bf16_t* __restrict__ wkl,
                         const bf16_t* __restrict__ wvh,
                         const float* __restrict__ bq, const float* __restrict__ bk,
                         const float* __restrict__ bv,
                         bf16_t* __restrict__ Qhi, bf16_t* __restrict__ Qlo,
                         bf16_t* __restrict__ Khi, bf16_t* __restrict__ Klo,
                         bf16_t* __restrict__ Vt) {
    int z = blockIdx.y;
    int b = z & 3, which = z >> 2;  // 0=Q, 1=K, 2=V (block-uniform branch)
    int mt = blockIdx.x & 7, sb = blockIdx.x >> 3;
    int wave = threadIdx.x >> 6, lane = threadIdx.x & 63;
    int l15 = lane & 15, quad = lane >> 4;

    if (which < 2) {
        const bf16_t* wh = which ? wkh : wqh;
        const bf16_t* wl = which ? wkl : wql;
        const float* bias = which ? bk : bq;
        bf16_t* outh = which ? Khi : Qhi;
        bf16_t* outl = which ? Klo : Qlo;
        int s0 = sb * 256 + wave * 64, m0 = mt * 64;
        const bf16_t* xhb = xh + ((size_t)b * Ss + s0 + l15) * Din + quad * 8;
        const bf16_t* xlb = xl + ((size_t)b * Ss + s0 + l15) * Din + quad * 8;
        const bf16_t* whb = wh + (size_t)(m0 + l15) * Din + quad * 8;
        const bf16_t* wlb = wl + (size_t)(m0 + l15) * Din + quad * 8;
        f32x4 acc[4][4] = {};  // [s-tile][m-tile]
        for (int ks = 0; ks < 8; ++ks) {
            bf16x8 ah[4], al[4], bh[4], bl[4];
#pragma unroll
            for (int st = 0; st < 4; ++st) {
                ah[st] = ldfrag(xhb + (size_t)st * 16 * Din + ks * 32);
                al[st] = ldfrag(xlb + (size_t)st * 16 * Din + ks * 32);
            }
#pragma unroll
            for (int nt = 0; nt < 4; ++nt) {
                bh[nt] = ldfrag(whb + (size_t)nt * 16 * Din + ks * 32);
                bl[nt] = ldfrag(wlb + (size_t)nt * 16 * Din + ks * 32);
            }
#pragma unroll
            for (int st = 0; st < 4; ++st)
#pragma unroll
                for (int nt = 0; nt < 4; ++nt) {
                    acc[st][nt] = MFMA16(ah[st], bh[nt], acc[st][nt]);
                    acc[st][nt] = MFMA16(ah[st], bl[nt], acc[st][nt]);
                    acc[st][nt] = MFMA16(al[st], bh[nt], acc[st][nt]);
                }
        }
        int h = m0 >> 6;  // head within this b
#pragma unroll
        for (int nt = 0; nt < 4; ++nt) {
            int m = m0 + nt * 16 + l15;
            float bb = bias[m];
            int d = m & 63;
#pragma unroll
            for (int st = 0; st < 4; ++st)
#pragma unroll
                for (int r = 0; r < 4; ++r) {
                    int s = s0 + st * 16 + quad * 4 + r;
                    float v = acc[st][nt][r] + bb;
                    bf16_t hh, ll;
                    fsplit(v, hh, ll);
                    size_t o = ((size_t)(b * Hh + h) * Ss + s) * Dk + d;
                    outh[o] = hh;
                    outl[o] = ll;
                }
        }
    } else {
        int m0 = mt * 64, s0 = sb * 256 + wave * 64;
        const bf16_t* ab = wvh + (size_t)(m0 + l15) * Din + quad * 8;
        const bf16_t* bb = xh + ((size_t)b * Ss + s0 + l15) * Din + quad * 8;
        f32x4 acc[4][4] = {};  // [m-tile][s-tile]
        for (int ks = 0; ks < 8; ++ks) {
            bf16x8 af[4], bf_[4];
#pragma unroll
            for (int i = 0; i < 4; ++i) {
                af[i] = ldfrag(ab + (size_t)i * 16 * Din + ks * 32);
                bf_[i] = ldfrag(bb + (size_t)i * 16 * Din + ks * 32);
            }
#pragma unroll
            for (int i = 0; i < 4; ++i)
#pragma unroll
                for (int j = 0; j < 4; ++j) acc[i][j] = MFMA16(af[i], bf_[j], acc[i][j]);
        }
#pragma unroll
        for (int i = 0; i < 4; ++i)
#pragma unroll
            for (int r = 0; r < 4; ++r) {
                int m = m0 + i * 16 + quad * 4 + r;
                float bvv = bv[m];
#pragma unroll
                for (int j = 0; j < 4; ++j) {
                    int s = s0 + j * 16 + l15;
                    Vt[((size_t)b * Dm + m) * Ss + s] = (bf16_t)(acc[i][j][r] + bvv);
                }
            }
    }
}

// ---------------------------------------------------------------------------
// attn_kernel: per (head, 64-q tile). Wave owns 16 q-rows, sweeps all 2048 keys.
// XCD-aware remap: blocks on XCD x handle heads [4x, 4x+4) only, so the per-XCD
// K/V working set is 4*(512+256)KB = 3MB <= 4MB L2 (was 24MB -> thrash).
// All 16 K fragments of a 64-key chunk are loaded before the MFMAs (MLP).
// No __syncthreads: pbuf is wave-private.
// ---------------------------------------------------------------------------
__global__ void attn_kernel(const bf16_t* __restrict__ Qhi, const bf16_t* __restrict__ Qlo,
                            const bf16_t* __restrict__ Khi, const bf16_t* __restrict__ Klo,
                            const bf16_t* __restrict__ Vt, bf16_t* __restrict__ AO,
                            float* __restrict__ attw) {
    __shared__ __align__(16) bf16_t pbuf[4][16][72];
    int bid = blockIdx.y * 32 + blockIdx.x;  // grid is (32, 32)
    int xcd = bid & 7, idx = bid >> 3;       // dispatch maps bid%8 -> XCD
    int head = xcd * 4 + (idx >> 5);         // 4 heads per XCD
    int qt = idx & 31;
    int wave = threadIdx.x >> 6, lane = threadIdx.x & 63;
    int l15 = lane & 15, quad = lane >> 4;
    int q0 = qt * 64 + wave * 16;

    const bf16_t* qh_p = Qhi + ((size_t)head * Ss + q0 + l15) * Dk + quad * 8;
    const bf16_t* ql_p = Qlo + ((size_t)head * Ss + q0 + l15) * Dk + quad * 8;
    bf16x8 qah[2], qal[2];
#pragma unroll
    for (int ks = 0; ks < 2; ++ks) {
        qah[ks] = ldfrag(qh_p + ks * 32);
        qal[ks] = ldfrag(ql_p + ks * 32);
    }
    const bf16_t* kh_b = Khi + (size_t)head * Ss * Dk;
    const bf16_t* kl_b = Klo + (size_t)head * Ss * Dk;
    const bf16_t* v_b  = Vt + (size_t)head * Dk * Ss;

    // ---- pass 1: row sums of exp(s) (no max trick: |s| <~ 16, fp32-safe) ----
    float lsum[4] = {0.f, 0.f, 0.f, 0.f};
    for (int kc = 0; kc < Ss; kc += 64) {
        bf16x8 kh[4][2], kl[4][2];
#pragma unroll
        for (int nt = 0; nt < 4; ++nt)
#pragma unroll
            for (int ks = 0; ks < 2; ++ks) {
                const bf16_t* base = kh_b + (size_t)(kc + nt * 16 + l15) * Dk + quad * 8;
                kh[nt][ks] = ldfrag(base + ks * 32);
                kl[nt][ks] = ldfrag(kl_b + (size_t)(kc + nt * 16 + l15) * Dk + quad * 8 + ks * 32);
            }
#pragma unroll
        for (int nt = 0; nt < 4; ++nt) {
            f32x4 sc = {0.f, 0.f, 0.f, 0.f};
#pragma unroll
            for (int ks = 0; ks < 2; ++ks) {
                sc = MFMA16(qah[ks], kh[nt][ks], sc);
                sc = MFMA16(qah[ks], kl[nt][ks], sc);
                sc = MFMA16(qal[ks], kh[nt][ks], sc);
            }
#pragma unroll
            for (int r = 0; r < 4; ++r) lsum[r] += __builtin_amdgcn_exp2f(sc[r] * LOG2E);
        }
    }
#pragma unroll
    for (int r = 0; r < 4; ++r) {  // merge across the 16 column-lanes
        float v = lsum[r];
        v += __shfl_xor(v, 1);
        v += __shfl_xor(v, 2);
        v += __shfl_xor(v, 4);
        v += __shfl_xor(v, 8);
        lsum[r] = v;
    }
    float linv[4];
#pragma unroll
    for (int r = 0; r < 4; ++r) linv[r] = 1.0f / lsum[r];

    // ---- pass 2 ----
    f32x4 oacc[4] = {};  // [d-tile] C[16q][16d]
    float* aw_base = attw + ((size_t)head * Ss + q0) * Ss;
    for (int kc = 0; kc < Ss; kc += 64) {
        bf16x8 kh[4][2], kl[4][2];
#pragma unroll
        for (int nt = 0; nt < 4; ++nt)
#pragma unroll
            for (int ks = 0; ks < 2; ++ks) {
                kh[nt][ks] = ldfrag(kh_b + (size_t)(kc + nt * 16 + l15) * Dk + quad * 8 + ks * 32);
                kl[nt][ks] = ldfrag(kl_b + (size_t)(kc + nt * 16 + l15) * Dk + quad * 8 + ks * 32);
            }
        f32x4 sc[4];
#pragma unroll
        for (int nt = 0; nt < 4; ++nt) {
            sc[nt] = f32x4{0.f, 0.f, 0.f, 0.f};
#pragma unroll
            for (int ks = 0; ks < 2; ++ks) {
                sc[nt] = MFMA16(qah[ks], kh[nt][ks], sc[nt]);
                sc[nt] = MFMA16(qah[ks], kl[nt][ks], sc[nt]);
                sc[nt] = MFMA16(qal[ks], kh[nt][ks], sc[nt]);
            }
        }
        // issue V loads now; they land while exp/stores run
        bf16x8 vb[2][4];
#pragma unroll
        for (int ks = 0; ks < 2; ++ks)
#pragma unroll
            for (int dt = 0; dt < 4; ++dt)
                vb[ks][dt] = ldfrag(v_b + (size_t)(dt * 16 + l15) * Ss + kc + ks * 32 + quad * 8);
#pragma unroll
        for (int nt = 0; nt < 4; ++nt) {
            int k0 = kc + nt * 16;
#pragma unroll
            for (int r = 0; r < 4; ++r) {
                float w = __builtin_amdgcn_exp2f(sc[nt][r] * LOG2E) * linv[r];
                int q = quad * 4 + r;
                __builtin_nontemporal_store(w, &aw_base[(size_t)q * Ss + k0 + l15]);
                pbuf[wave][q][nt * 16 + l15] = (bf16_t)w;
            }
        }
        // P @ V over this 64-key chunk (pbuf is wave-private; lgkmcnt handles RAW)
#pragma unroll
        for (int ks = 0; ks < 2; ++ks) {
            bf16x8 pa = *reinterpret_cast<const bf16x8*>(&pbuf[wave][l15][ks * 32 + quad * 8]);
#pragma unroll
            for (int dt = 0; dt < 4; ++dt) oacc[dt] = MFMA16(pa, vb[ks][dt], oacc[dt]);
        }
    }
    // store AO: flat [s'][n][d] bf16 (torch-faithful flat layout)
#pragma unroll
    for (int dt = 0; dt < 4; ++dt)
#pragma unroll
        for (int r = 0; r < 4; ++r) {
            int q = q0 + quad * 4 + r;
            int col = head * Dk + dt * 16 + l15;
            AO[(size_t)q * (NHd * Dk) + col] = (bf16_t)oacc[dt][r];
        }
}

// ---------------------------------------------------------------------------
// out_kernel: Z[b][i][s] = sum_e Wo[i][e] * AO_scrambled[b][s][e] + bo[i]
// AO row base for (b,s): (b*512 + s/4)*2048 + (s%4)*512  (contiguous in e!)
// Wave tile 32i x 64s -> 1024 waves (4/CU) instead of 512 (2/CU).
// ---------------------------------------------------------------------------
__global__ void out_kernel(const bf16_t* __restrict__ AO, const bf16_t* __restrict__ woh,
                           const float* __restrict__ bo, float* __restrict__ Z) {
    int b = blockIdx.z, it = blockIdx.y, sb = blockIdx.x;  // grid (32, 2, 4)
    int wave = threadIdx.x >> 6, lane = threadIdx.x & 63;
    int l15 = lane & 15, quad = lane >> 4;
    int i0 = it * 128 + wave * 32, s0 = sb * 64;
    const bf16_t* wop = woh + (size_t)(i0 + l15) * Dm + quad * 8;
    size_t bbase[4];
#pragma unroll
    for (int nt = 0; nt < 4; ++nt) {
        int s = s0 + nt * 16 + l15;
        bbase[nt] = ((size_t)(b * 512 + (s >> 2)) * 2048) + (size_t)(s & 3) * 512 + quad * 8;
    }
    f32x4 acc[2][4] = {};  // [i-tile][s-tile]
    for (int ks = 0; ks < 16; ++ks) {
        bf16x8 af[2], bf_[4];
#pragma unroll
        for (int mt = 0; mt < 2; ++mt) af[mt] = ldfrag(wop + (size_t)mt * 16 * Dm + ks * 32);
#pragma unroll
        for (int nt = 0; nt < 4; ++nt) bf_[nt] = ldfrag(AO + bbase[nt] + ks * 32);
#pragma unroll
        for (int mt = 0; mt < 2; ++mt)
#pragma unroll
            for (int nt = 0; nt < 4; ++nt) acc[mt][nt] = MFMA16(af[mt], bf_[nt], acc[mt][nt]);
    }
#pragma unroll
    for (int mt = 0; mt < 2; ++mt)
#pragma unroll
        for (int r = 0; r < 4; ++r) {
            int i = i0 + mt * 16 + quad * 4 + r;
            float bias = bo[i];
#pragma unroll
            for (int nt = 0; nt < 4; ++nt) {
                int s = s0 + nt * 16 + l15;
                __builtin_nontemporal_store(acc[mt][nt][r] + bias,
                                            &Z[((size_t)b * Din + i) * Ss + s]);
            }
        }
}

// ---------------------------------------------------------------------------
extern "C" void kernel_launch(void* const* d_in, const int* in_sizes, int n_in,
                              void* d_out, int out_size, void* d_ws, size_t ws_size,
                              hipStream_t stream) {
    const float* x  = (const float*)d_in[0];
    const float* Wq = (const float*)d_in[1];
    const float* bq = (const float*)d_in[2];
    const float* Wk = (const float*)d_in[3];
    const float* bk = (const float*)d_in[4];
    const float* Wv = (const float*)d_in[5];
    const float* bv = (const float*)d_in[6];
    const float* Wo = (const float*)d_in[7];
    const float* bo = (const float*)d_in[8];

    float* Z    = (float*)d_out;
    float* attw = Z + (size_t)Bb * Din * Ss;  // 2,097,152 floats in

    char* ws = (char*)d_ws;
    constexpr size_t SZ_XT = (size_t)Bb * Ss * Din * 2;   // 4 MB
    constexpr size_t SZ_W  = (size_t)Dm * Din * 2;        // 256 KB
    constexpr size_t SZ_Q  = (size_t)NHd * Ss * Dk * 2;   // 8 MB
    bf16_t* xh  = (bf16_t*)(ws);
    bf16_t* xl  = (bf16_t*)(ws + SZ_XT);
    bf16_t* wqh = (bf16_t*)(ws + 2 * SZ_XT);
    bf16_t* wql = (bf16_t*)(ws + 2 * SZ_XT + SZ_W);
    bf16_t* wkh = (bf16_t*)(ws + 2 * SZ_XT + 2 * SZ_W);
    bf16_t* wkl = (bf16_t*)(ws + 2 * SZ_XT + 3 * SZ_W);
    bf16_t* wvh = (bf16_t*)(ws + 2 * SZ_XT + 4 * SZ_W);
    bf16_t* woh = (bf16_t*)(ws + 2 * SZ_XT + 5 * SZ_W);
    char* p2 = ws + 2 * SZ_XT + 6 * SZ_W;
    bf16_t* Qhi = (bf16_t*)(p2);
    bf16_t* Qlo = (bf16_t*)(p2 + SZ_Q);
    bf16_t* Khi = (bf16_t*)(p2 + 2 * SZ_Q);
    bf16_t* Klo = (bf16_t*)(p2 + 3 * SZ_Q);
    bf16_t* Vt  = (bf16_t*)(p2 + 4 * SZ_Q);
    bf16_t* AO  = (bf16_t*)(p2 + 5 * SZ_Q);

    prep_x<<<dim3(Ss / 32, Din / 32, Bb), dim3(32, 8), 0, stream>>>(x, xh, xl);
    prep_w<<<dim3((Dm * Din) / 256), dim3(256), 0, stream>>>(Wq, Wk, Wv, Wo, wqh, wql, wkh,
                                                             wkl, wvh, woh);
    proj_qkv<<<dim3(64, 12), dim3(256), 0, stream>>>(xh, xl, wqh, wql, wkh, wkl, wvh,
                                                     bq, bk, bv, Qhi, Qlo, Khi, Klo, Vt);
    attn_kernel<<<dim3(32, 32), dim3(256), 0, stream>>>(Qhi, Qlo, Khi, Klo, Vt, AO, attw);
    out_kernel<<<dim3(32, 2, 4), dim3(256), 0, stream>>>(AO, woh, bo, Z);
}